// Round 5
// baseline (248.965 us; speedup 1.0000x reference)
//
#include <hip/hip_runtime.h>

// Problem constants
#define BB   128
#define DD   2048
#define NN   2048
#define LL   4
#define OUTN 1024
#define NB   (NN * BB)
#define KC   32            // k per LDS chunk
#define PADW 34            // doubles per n-row in LDS W tile (32 + 2 pad)

typedef double double4v __attribute__((ext_vector_type(4)));

// ---------------------------------------------------------------------------
// Layer-0 transpose-gather: At[k][b] = x[b, axon_idx0[k]]
// ---------------------------------------------------------------------------
__global__ __launch_bounds__(256) void gather0_kernel(
    const float* __restrict__ x, const int* __restrict__ idx0,
    float* __restrict__ At)
{
    int i = blockIdx.x * 256 + threadIdx.x;   // over DD*BB
    int k = i >> 7;
    int b = i & 127;
    At[i] = x[b * DD + idx0[k]];
}

// ---------------------------------------------------------------------------
// fp64 MFMA GEMM: parts[split][n][b] = sum_k W[n][k] * src[row(k)][b]
// Block 256 thr = 4 waves. Block tile: n=64, b=64 (wave wq: b = 16*wq..+16).
// DOUBLE-BUFFERED LDS W-tile: stage chunk c+1 into buf[(c+1)&1] while
// computing from buf[c&1]; ONE barrier per chunk (parity reuse separated by
// the previous barrier). A: global->regs->LDS 2-deep pipeline. B: per-lane
// global loads (L2-resident), 2-deep register pipeline.
// D-fragment layout DISCOVERED AT RUNTIME via two probe MFMAs.
// ---------------------------------------------------------------------------
__global__ __launch_bounds__(256, 4) void gemm_mfma64(
    const float* __restrict__ srcT,   // [row(2048)][BB] fp32
    const int*   __restrict__ idx,    // nullptr => identity rows
    const float* __restrict__ Wl,     // [n][k] row-major
    double*      __restrict__ parts,  // [nsplit][NN][BB]
    int krange)
{
    __shared__ __align__(16) double Wq[2][64 * PADW];   // 2 x 17.4 KB

    const int t     = threadIdx.x;
    const int nsup  = blockIdx.x;          // n / 64
    const int bsup  = blockIdx.y;          // b / 64
    const int split = blockIdx.z;
    const int n0b   = nsup * 64;
    const int k0s   = split * krange;
    const int wq    = t >> 6;
    const int lane  = t & 63;
    const int q     = lane >> 4;           // assumed k-quad
    const int c     = lane & 15;           // assumed m (A) / n (B) coordinate
    const int b0w   = bsup * 64 + wq * 16;

    // ---- runtime D-layout probe (layout-agnostic store) ----
    double4v pr = {0., 0., 0., 0.}, pc = {0., 0., 0., 0.};
    pr = __builtin_amdgcn_mfma_f64_16x16x4f64(0.25 * (double)c, 1.0, pr, 0, 0, 0);
    pc = __builtin_amdgcn_mfma_f64_16x16x4f64(0.25, (double)c, pc, 0, 0, 0);
    int rowD[4], colD[4];
    #pragma unroll
    for (int r = 0; r < 4; ++r) {
        rowD[r] = (int)(pr[r] + 0.25);
        colD[r] = (int)(pc[r] + 0.25);
    }

    // staging decomposition: thread stages rows sn and sn+32, float4 sm
    const int sn = t >> 3;                 // 0..31
    const int sm = t & 7;                  // 0..7

    double4v acc[4] = {{0.,0.,0.,0.},{0.,0.,0.,0.},{0.,0.,0.,0.},{0.,0.,0.,0.}};

    const int nchunk = krange / KC;

    // ---- prologue ----
    // A(0) + B(0)
    float4 a0 = *(const float4*)(Wl + (size_t)(n0b + sn) * DD + k0s + 4 * sm);
    float4 a1 = *(const float4*)(Wl + (size_t)(n0b + sn + 32) * DD + k0s + 4 * sm);
    float bF[8], bN[8];
    #pragma unroll
    for (int j = 0; j < 8; ++j) {
        int k = k0s + 4 * j + q;
        int row = idx ? idx[k] : k;
        bF[j] = srcT[(size_t)row * BB + b0w + c];
    }
    // stage buf0 <- A(0)
    {
        const float* f0 = (const float*)&a0;
        const float* f1 = (const float*)&a1;
        double* w0 = Wq[0] + sn * PADW + sm;
        double* w1 = Wq[0] + (sn + 32) * PADW + sm;
        #pragma unroll
        for (int i = 0; i < 4; ++i) {
            w0[i * 8] = (double)f0[i];
            w1[i * 8] = (double)f1[i];
        }
    }
    // A(1) + B(1) into regs
    if (nchunk > 1) {
        const float* p = Wl + (size_t)(n0b + sn) * DD + k0s + KC + 4 * sm;
        a0 = *(const float4*)p;
        a1 = *(const float4*)(p + (size_t)32 * DD);
        #pragma unroll
        for (int j = 0; j < 8; ++j) {
            int k = k0s + KC + 4 * j + q;
            int row = idx ? idx[k] : k;
            bN[j] = srcT[(size_t)row * BB + b0w + c];
        }
    }
    __syncthreads();

    for (int ch = 0; ch < nchunk; ++ch) {
        double* buf = Wq[ch & 1];
        // stage next chunk into the other buffer (waits on aReg loads)
        if (ch + 1 < nchunk) {
            const float* f0 = (const float*)&a0;
            const float* f1 = (const float*)&a1;
            double* w0 = Wq[(ch + 1) & 1] + sn * PADW + sm;
            double* w1 = Wq[(ch + 1) & 1] + (sn + 32) * PADW + sm;
            #pragma unroll
            for (int i = 0; i < 4; ++i) {
                w0[i * 8] = (double)f0[i];
                w1[i * 8] = (double)f1[i];
            }
        }
        // prefetch A(ch+2) into regs
        if (ch + 2 < nchunk) {
            const float* p = Wl + (size_t)(n0b + sn) * DD + k0s + (ch + 2) * KC + 4 * sm;
            a0 = *(const float4*)p;
            a1 = *(const float4*)(p + (size_t)32 * DD);
        }

        // compute chunk ch from buf, B from bF
        #pragma unroll
        for (int jp = 0; jp < 4; ++jp) {
            double2 wf[4];
            #pragma unroll
            for (int tt = 0; tt < 4; ++tt)
                wf[tt] = *(const double2*)(buf + (16 * tt + c) * PADW + q * 8 + 2 * jp);
            double bv0 = (double)bF[2 * jp];
            double bv1 = (double)bF[2 * jp + 1];
            #pragma unroll
            for (int tt = 0; tt < 4; ++tt)
                acc[tt] = __builtin_amdgcn_mfma_f64_16x16x4f64(wf[tt].x, bv0, acc[tt], 0, 0, 0);
            #pragma unroll
            for (int tt = 0; tt < 4; ++tt)
                acc[tt] = __builtin_amdgcn_mfma_f64_16x16x4f64(wf[tt].y, bv1, acc[tt], 0, 0, 0);
        }

        // rotate B pipeline; prefetch B(ch+2)
        #pragma unroll
        for (int j = 0; j < 8; ++j) bF[j] = bN[j];
        if (ch + 2 < nchunk) {
            int k0n = k0s + (ch + 2) * KC;
            #pragma unroll
            for (int j = 0; j < 8; ++j) {
                int k = k0n + 4 * j + q;
                int row = idx ? idx[k] : k;
                bN[j] = srcT[(size_t)row * BB + b0w + c];
            }
        }
        __syncthreads();   // single barrier per chunk
    }

    // store via probed layout: n = n0b + 16*tt + rowD[r], b = b0w + colD[r]
    #pragma unroll
    for (int tt = 0; tt < 4; ++tt) {
        #pragma unroll
        for (int r = 0; r < 4; ++r) {
            int n = n0b + 16 * tt + rowD[r];
            size_t o = ((size_t)split * NN + n) * BB + b0w + colD[r];
            parts[o] = acc[tt][r];
        }
    }
}

// ---------------------------------------------------------------------------
// Spike-count scan (deterministic fixed-order split reduction), 2 elems/thread.
// ---------------------------------------------------------------------------
__global__ __launch_bounds__(256) void spike_kernel(
    const double* __restrict__ parts, const float* __restrict__ thresholds,
    int l, const int* __restrict__ Tptr,
    float* __restrict__ meanT, float* __restrict__ cntT, int nsplit)
{
    int i0 = blockIdx.x * 256 + threadIdx.x;   // 0 .. NB/2-1
    int i1 = i0 + NB / 2;
    double a0 = 0.0, a1 = 0.0;
    for (int s = 0; s < nsplit; ++s) {
        a0 += parts[(size_t)s * NB + i0];
        a1 += parts[(size_t)s * NB + i1];
    }
    const double thr = (double)thresholds[l];
    const int T = *Tptr;
    double m0 = 0.0, m1 = 0.0;
    int c0 = 0, c1 = 0;
    for (int t = 0; t < T; ++t) {
        m0 += a0;
        m1 += a1;
        if (m0 > thr) { c0++; m0 -= thr; }
        if (m1 > thr) { c1++; m1 -= thr; }
    }
    if (l == LL - 1) {
        cntT[i0] = (float)c0;
        cntT[i1] = (float)c1;
    } else {
        meanT[i0] = (float)c0 / (float)T;   // exact in fp32 (T=64)
        meanT[i1] = (float)c1 / (float)T;
    }
}

// ---------------------------------------------------------------------------
// Output gather: out[b, o] = cntT[out_idx[o]][b]
// ---------------------------------------------------------------------------
__global__ __launch_bounds__(256) void out_kernel(
    const float* __restrict__ cntT, const int* __restrict__ out_idx,
    float* __restrict__ out)
{
    int i = blockIdx.x * 256 + threadIdx.x;   // over BB*OUTN
    int b = i >> 10;
    int o = i & 1023;
    out[i] = cntT[(size_t)out_idx[o] * BB + b];
}

extern "C" void kernel_launch(void* const* d_in, const int* in_sizes, int n_in,
                              void* d_out, int out_size, void* d_ws, size_t ws_size,
                              hipStream_t stream)
{
    const float* x    = (const float*)d_in[0];
    const float* W    = (const float*)d_in[1];
    const float* thr  = (const float*)d_in[2];
    const int*   axon = (const int*)d_in[3];
    const int*   oidx = (const int*)d_in[4];
    const int*   Tptr = (const int*)d_in[5];
    float* out = (float*)d_out;

    char* ws = (char*)d_ws;
    float*  At    = (float*)ws;                    // 1 MB  [D][B]
    float*  meanT = (float*)(ws + (1u << 20));     // 1 MB  [N][B]
    float*  cntT  = (float*)(ws + (2u << 20));     // 1 MB  [N][B]
    double* parts = (double*)(ws + (3u << 20));    // nsplit * 2 MB

    // adaptive K-split: largest power of 2 <= 16 whose parts fit in ws
    int nsplit = 16;
    while (nsplit > 1 &&
           (size_t)nsplit * NB * sizeof(double) + (3u << 20) > ws_size)
        nsplit >>= 1;
    const int krange = DD / nsplit;    // multiple of KC for nsplit <= 64

    gather0_kernel<<<(DD * BB) / 256, 256, 0, stream>>>(x, axon, At);

    for (int l = 0; l < LL; ++l) {
        const float* srcT = (l == 0) ? At : meanT;
        const int*   idx  = (l == 0) ? nullptr : (axon + (size_t)l * DD);
        gemm_mfma64<<<dim3(NN / 64, BB / 64, nsplit), 256, 0, stream>>>(
            srcT, idx, W + (size_t)l * NN * DD, parts, krange);
        spike_kernel<<<NB / 512, 256, 0, stream>>>(
            parts, thr, l, Tptr, meanT, cntT, nsplit);
    }

    out_kernel<<<(BB * OUTN) / 256, 256, 0, stream>>>(cntT, oidx, out);
}